// Round 2
// baseline (719.446 us; speedup 1.0000x reference)
//
#include <hip/hip_runtime.h>
#include <hip/hip_bf16.h>
#include <stdint.h>

constexpr int Bb = 32;
constexpr int Ll = 1024;
constexpr int Hh = 512;

typedef __attribute__((ext_vector_type(8))) short short8;
typedef __attribute__((ext_vector_type(4))) short short4v;
typedef __attribute__((ext_vector_type(4))) float float4v;
typedef __attribute__((ext_vector_type(4))) int int4v;

__device__ inline short f2bf(float f) {
  union { float f; uint32_t u; } v; v.f = f;
  uint32_t r = (v.u + 0x7FFF + ((v.u >> 16) & 1)) >> 16;
  return (short)r;
}

#define MFMA(a, b, c) __builtin_amdgcn_mfma_f32_16x16x32_bf16(a, b, c, 0, 0, 0)

// async 16B global->LDS (dest = wave-uniform base + lane*16)
__device__ inline void gl_lds(const short* g, short* l) {
  __builtin_amdgcn_global_load_lds(
      (const __attribute__((address_space(1))) unsigned int*)g,
      (__attribute__((address_space(3))) unsigned int*)l, 16, 0, 0);
}

// Stage ROWS x 64 bf16 tile from row-major global (stride sk) into LDS.
// LDS layout: lds[row*64 + (kb ^ (row&7))*8 .. +8] = g[row*sk + kb*8 .. +8]
template <int ROWS>
__device__ inline void stage(short* lds, const short* g, int sk, int t) {
  const int w = t >> 6;
  const int kbg = (t & 7) ^ ((t >> 3) & 7);
#pragma unroll
  for (int r = 0; r < ROWS / 32; ++r) {
    int row = r * 32 + (t >> 3);
    gl_lds(g + (size_t)row * sk + kbg * 8, lds + (r * 32 + w * 8) * 64);
  }
}

// fragment load: 8 contiguous bf16 (k) for row, k-block kb (global k index kb*8)
__device__ inline short8 fld(const short* lds, int row, int kb) {
  return *(const short8*)(lds + row * 64 + ((kb ^ (row & 7)) << 3));
}

// ---------------------------------------------------------------------------
// per-row dots  s0[b,l] = c.cw,  s1[b,l] = c.qw
__global__ __launch_bounds__(256) void k_rowdots(
    const float* __restrict__ c, const float* __restrict__ cw,
    const float* __restrict__ qw, float* __restrict__ s0, float* __restrict__ s1) {
  int row = blockIdx.x * 4 + (threadIdx.x >> 6);
  int lane = threadIdx.x & 63;
  const float* cr = c + (size_t)row * Hh;
  float d0 = 0.f, d1 = 0.f;
#pragma unroll
  for (int i = 0; i < Hh / 64; ++i) {
    int h = lane + i * 64;
    float v = cr[h];
    d0 = fmaf(v, cw[h], d0);
    d1 = fmaf(v, qw[h], d1);
  }
#pragma unroll
  for (int off = 32; off > 0; off >>= 1) {
    d0 += __shfl_down(d0, off);
    d1 += __shfl_down(d1, off);
  }
  if (lane == 0) { s0[row] = d0; s1[row] = d1; }
}

// ---------------------------------------------------------------------------
// FUSED prep: one read of c ->
//   cT16[b][h][l] (bf16 transpose), c16 = bf16(c), cbq16 = bf16(c*cq)
__global__ __launch_bounds__(256) void k_ct(
    const float* __restrict__ c, const float* __restrict__ cq,
    short* __restrict__ cT, short* __restrict__ c16, short* __restrict__ cbq16) {
  const int b = blockIdx.z, h0 = blockIdx.x * 64, l0 = blockIdx.y * 64;
  __shared__ short T[64 * 65];
  const int t = threadIdx.x, rl = t >> 4, c4 = (t & 15) * 4;
  float4v qv = *(const float4v*)&cq[h0 + c4];
#pragma unroll
  for (int p = 0; p < 4; ++p) {
    int ll = rl + p * 16;
    size_t gi = ((size_t)(b * Ll + l0 + ll)) * Hh + h0 + c4;
    float4v v = *(const float4v*)&c[gi];
    short4v o, oq;
#pragma unroll
    for (int j = 0; j < 4; ++j) {
      short bv = f2bf(v[j]);
      T[ll * 65 + c4 + j] = bv;
      o[j] = bv;
      oq[j] = f2bf(v[j] * qv[j]);
    }
    *(short4v*)&c16[gi] = o;
    *(short4v*)&cbq16[gi] = oq;
  }
  __syncthreads();
#pragma unroll
  for (int p = 0; p < 4; ++p) {
    int hh = rl + p * 16;
    short4v o;
#pragma unroll
    for (int j = 0; j < 4; ++j) o[j] = T[(c4 + j) * 65 + hh];
    *(short4v*)&cT[((size_t)(b * Hh + h0 + hh)) * Ll + l0 + c4] = o;
  }
}

// ---------------------------------------------------------------------------
// S = cbq16 @ c16^T + s0 + s1 + bias   (fp32 out)
// 2-phase double-buffered staging; fused row/col softmax partial stats.
__global__ __launch_bounds__(256) void k_sgemm(
    const short* __restrict__ Aq, const short* __restrict__ Bc,
    const float* __restrict__ s0, const float* __restrict__ s1,
    const float* __restrict__ bias, const int* __restrict__ c_mask,
    float* __restrict__ S,
    float* __restrict__ rowpmax, float* __restrict__ rowpsum,
    float* __restrict__ colpmax, float* __restrict__ colpsum) {
  // XCD-chunked swizzle (nwg=2048, 256 consecutive units per XCD)
  int flat = blockIdx.x + ((blockIdx.y + (blockIdx.z << 3)) << 3);
  flat = ((flat & 7) << 8) | (flat >> 3);
  const int b = flat >> 6, l0 = ((flat >> 3) & 7) << 7, m0 = (flat & 7) << 7;
  __shared__ __align__(16) short As[2][128 * 64];
  __shared__ __align__(16) short Bs[2][128 * 64];
  const int t = threadIdx.x, li = t & 63, w = t >> 6;
  const int wy = w >> 1, wx = w & 1, rr = li & 15, q = li >> 4;
  const short* Ag = Aq + ((size_t)b * Ll + l0) * Hh;
  const short* Bg = Bc + ((size_t)b * Ll + m0) * Hh;
  float4v acc[4][4];
#pragma unroll
  for (int i = 0; i < 4; ++i)
#pragma unroll
    for (int j = 0; j < 4; ++j) acc[i][j] = (float4v){0.f, 0.f, 0.f, 0.f};
  stage<128>(As[0], Ag, Hh, t);
  stage<128>(Bs[0], Bg, Hh, t);
  __syncthreads();
  for (int it = 0; it < Hh / 64; ++it) {
    if (it + 1 < Hh / 64) {
      stage<128>(As[(it + 1) & 1], Ag + (it + 1) * 64, Hh, t);
      stage<128>(Bs[(it + 1) & 1], Bg + (it + 1) * 64, Hh, t);
    }
    const short* Ab = As[it & 1];
    const short* Bbuf = Bs[it & 1];
#pragma unroll
    for (int ks = 0; ks < 2; ++ks) {
      int kb = ks * 4 + q;
      short8 af[4], bf4[4];
#pragma unroll
      for (int mt = 0; mt < 4; ++mt) af[mt] = fld(Ab, wy * 64 + mt * 16 + rr, kb);
#pragma unroll
      for (int nt = 0; nt < 4; ++nt) bf4[nt] = fld(Bbuf, wx * 64 + nt * 16 + rr, kb);
#pragma unroll
      for (int mt = 0; mt < 4; ++mt)
#pragma unroll
        for (int nt = 0; nt < 4; ++nt)
          acc[mt][nt] = MFMA(af[mt], bf4[nt], acc[mt][nt]);
    }
    __syncthreads();
  }
  // ---- epilogue: finalize S in registers ----
  const float bsc = bias[0];
  float s1v[4]; int mkm[4];
#pragma unroll
  for (int nt = 0; nt < 4; ++nt) {
    int m = m0 + wx * 64 + nt * 16 + rr;
    s1v[nt] = s1[b * Ll + m] + bsc;
    mkm[nt] = c_mask[b * Ll + m];
  }
  int mkl[4][4];
#pragma unroll
  for (int mt = 0; mt < 4; ++mt)
#pragma unroll
    for (int i = 0; i < 4; ++i) {
      int l = l0 + wy * 64 + mt * 16 + q * 4 + i;
      float s0v = s0[b * Ll + l];
      mkl[mt][i] = c_mask[b * Ll + l];
#pragma unroll
      for (int nt = 0; nt < 4; ++nt) acc[mt][nt][i] += s0v + s1v[nt];
    }
  // store S
  float* Sb = S + (size_t)b * Ll * Ll;
#pragma unroll
  for (int nt = 0; nt < 4; ++nt) {
    int m = m0 + wx * 64 + nt * 16 + rr;
#pragma unroll
    for (int mt = 0; mt < 4; ++mt)
#pragma unroll
      for (int i = 0; i < 4; ++i) {
        int l = l0 + wy * 64 + mt * 16 + q * 4 + i;
        Sb[(size_t)l * Ll + m] = acc[mt][nt][i];
      }
  }
  // ---- fused softmax partial stats (tile live in acc) ----
  float* red = (float*)As;  // 256-float scratch; k-loop LDS use is done
  const size_t rbase = (size_t)(m0 >> 7) * (Bb * Ll) + (size_t)b * Ll + l0;
  const size_t cbase = (size_t)(l0 >> 7) * (Bb * Ll) + (size_t)b * Ll + m0;
  // row max over the tile's 128 columns (mask on m)
  float rv[16];
#pragma unroll
  for (int mt = 0; mt < 4; ++mt)
#pragma unroll
    for (int i = 0; i < 4; ++i) {
      float v = -INFINITY;
#pragma unroll
      for (int nt = 0; nt < 4; ++nt) v = mkm[nt] ? fmaxf(v, acc[mt][nt][i]) : v;
      rv[mt * 4 + i] = v;
    }
#pragma unroll
  for (int off = 1; off < 16; off <<= 1)
#pragma unroll
    for (int j = 0; j < 16; ++j) rv[j] = fmaxf(rv[j], __shfl_xor(rv[j], off));
  if (rr == 0)
#pragma unroll
    for (int j = 0; j < 16; ++j)
      red[wx * 128 + wy * 64 + (j >> 2) * 16 + q * 4 + (j & 3)] = rv[j];
  __syncthreads();
  if (t < 128) {
    float M = fmaxf(red[t], red[128 + t]);
    red[t] = M;
    rowpmax[rbase + t] = M;
  }
  __syncthreads();
  // row sumexp vs tile max
#pragma unroll
  for (int mt = 0; mt < 4; ++mt)
#pragma unroll
    for (int i = 0; i < 4; ++i) {
      float M = red[wy * 64 + mt * 16 + q * 4 + i];
      float sacc = 0.f;
      if (M > -INFINITY) {
#pragma unroll
        for (int nt = 0; nt < 4; ++nt)
          sacc += mkm[nt] ? __expf(acc[mt][nt][i] - M) : 0.f;
      }
      rv[mt * 4 + i] = sacc;
    }
#pragma unroll
  for (int off = 1; off < 16; off <<= 1)
#pragma unroll
    for (int j = 0; j < 16; ++j) rv[j] += __shfl_xor(rv[j], off);
  __syncthreads();
  if (rr == 0)
#pragma unroll
    for (int j = 0; j < 16; ++j)
      red[wx * 128 + wy * 64 + (j >> 2) * 16 + q * 4 + (j & 3)] = rv[j];
  __syncthreads();
  if (t < 128) rowpsum[rbase + t] = red[t] + red[128 + t];
  // col max over the tile's 128 rows (mask on l)
  float cv[4];
#pragma unroll
  for (int nt = 0; nt < 4; ++nt) {
    float v = -INFINITY;
#pragma unroll
    for (int mt = 0; mt < 4; ++mt)
#pragma unroll
      for (int i = 0; i < 4; ++i) v = mkl[mt][i] ? fmaxf(v, acc[mt][nt][i]) : v;
    cv[nt] = v;
  }
#pragma unroll
  for (int nt = 0; nt < 4; ++nt) {
    cv[nt] = fmaxf(cv[nt], __shfl_xor(cv[nt], 16));
    cv[nt] = fmaxf(cv[nt], __shfl_xor(cv[nt], 32));
  }
  __syncthreads();
  if (q == 0)
#pragma unroll
    for (int nt = 0; nt < 4; ++nt) red[wy * 128 + wx * 64 + nt * 16 + rr] = cv[nt];
  __syncthreads();
  if (t < 128) {
    float M = fmaxf(red[t], red[128 + t]);
    red[t] = M;
    colpmax[cbase + t] = M;
  }
  __syncthreads();
  // col sumexp vs tile max
#pragma unroll
  for (int nt = 0; nt < 4; ++nt) {
    float M = red[wx * 64 + nt * 16 + rr];
    float sacc = 0.f;
    if (M > -INFINITY) {
#pragma unroll
      for (int mt = 0; mt < 4; ++mt)
#pragma unroll
        for (int i = 0; i < 4; ++i)
          sacc += mkl[mt][i] ? __expf(acc[mt][nt][i] - M) : 0.f;
    }
    cv[nt] = sacc;
  }
#pragma unroll
  for (int nt = 0; nt < 4; ++nt) {
    cv[nt] += __shfl_xor(cv[nt], 16);
    cv[nt] += __shfl_xor(cv[nt], 32);
  }
  __syncthreads();
  if (q == 0)
#pragma unroll
    for (int nt = 0; nt < 4; ++nt) red[wy * 128 + wx * 64 + nt * 16 + rr] = cv[nt];
  __syncthreads();
  if (t < 128) colpsum[cbase + t] = red[t] + red[128 + t];
}

// ---------------------------------------------------------------------------
// combine 8 chunked partials -> max + 1/sum; blockIdx.y: 0=row stats, 1=col
__global__ __launch_bounds__(256) void k_comb2(
    const float* __restrict__ rpm, const float* __restrict__ rps,
    const float* __restrict__ cpm, const float* __restrict__ cps,
    float* __restrict__ rmax, float* __restrict__ rrcp,
    float* __restrict__ cmax, float* __restrict__ crcp) {
  int i = blockIdx.x * 256 + threadIdx.x;
  const float* pmax = blockIdx.y ? cpm : rpm;
  const float* psum = blockIdx.y ? cps : rps;
  float* omax = blockIdx.y ? cmax : rmax;
  float* orcp = blockIdx.y ? crcp : rrcp;
  float M = -INFINITY;
#pragma unroll
  for (int k = 0; k < 8; ++k) M = fmaxf(M, pmax[k * (Bb * Ll) + i]);
  float s = 0.f;
#pragma unroll
  for (int k = 0; k < 8; ++k) {
    float pm = pmax[k * (Bb * Ll) + i];
    if (pm > -INFINITY) s += psum[k * (Bb * Ll) + i] * __expf(pm - M);
  }
  omax[i] = M;
  orcp[i] = 1.f / s;
}

// ---------------------------------------------------------------------------
// FUSED softmax emit: one S read ->
//   P1[b][l][m]  = mask[m]*exp(S-rowmax[l])*rowrcp[l]   (bf16, direct)
//   P2T[b][m][l] = mask[l]*exp(S-colmax[m])*colrcp[m]   (bf16, transposed)
__global__ __launch_bounds__(256) void k_p12(
    const float* __restrict__ S, const int* __restrict__ c_mask,
    const float* __restrict__ rowmax, const float* __restrict__ rowrcp,
    const float* __restrict__ colmax, const float* __restrict__ colrcp,
    short* __restrict__ P1, short* __restrict__ P2T) {
  const int b = blockIdx.z, m0 = blockIdx.x * 64, l0 = blockIdx.y * 64;
  __shared__ short T[64 * 65];
  const int t = threadIdx.x, rl = t >> 4, c4 = (t & 15) * 4;
  const float* Sb = S + (size_t)b * Ll * Ll;
  float4v cm = *(const float4v*)&colmax[b * Ll + m0 + c4];
  float4v cr = *(const float4v*)&colrcp[b * Ll + m0 + c4];
  int4v mkm = *(const int4v*)&c_mask[b * Ll + m0 + c4];
#pragma unroll
  for (int p = 0; p < 4; ++p) {
    int ll = rl + p * 16;
    int gl = b * Ll + l0 + ll;
    int mkl = c_mask[gl];
    float rm = rowmax[gl], rrc = rowrcp[gl];
    float4v v = *(const float4v*)&Sb[(size_t)(l0 + ll) * Ll + m0 + c4];
    short4v o1;
#pragma unroll
    for (int j = 0; j < 4; ++j) {
      o1[j] = mkm[j] ? f2bf(__expf(v[j] - rm) * rrc) : (short)0;
      T[ll * 65 + c4 + j] = mkl ? f2bf(__expf(v[j] - cm[j]) * cr[j]) : (short)0;
    }
    *(short4v*)&P1[(size_t)gl * Ll + m0 + c4] = o1;
  }
  __syncthreads();
#pragma unroll
  for (int p = 0; p < 4; ++p) {
    int mm = rl + p * 16;
    short4v o;
#pragma unroll
    for (int j = 0; j < 4; ++j) o[j] = T[(c4 + j) * 65 + mm];
    *(short4v*)&P2T[((size_t)(b * Ll + m0 + mm)) * Ll + l0 + c4] = o;
  }
}

// ---------------------------------------------------------------------------
// uT[b][h][m] = (P2T @ cT^T)^T  bf16   (2-phase double-buffered)
__global__ __launch_bounds__(256) void k_ugemm(
    const short* __restrict__ P2T, const short* __restrict__ cT,
    short* __restrict__ uT) {
  // XCD-chunked swizzle (nwg=1024, 128 consecutive units per XCD)
  int flat = blockIdx.x + ((blockIdx.y + (blockIdx.z << 3)) << 2);
  flat = ((flat & 7) << 7) | (flat >> 3);
  const int b = flat >> 5, m0 = ((flat >> 2) & 7) << 7, h0 = (flat & 3) << 7;
  __shared__ __align__(16) short As[2][128 * 64];
  __shared__ __align__(16) short Bs[2][128 * 64];
  const int t = threadIdx.x, li = t & 63, w = t >> 6;
  const int wy = w >> 1, wx = w & 1, rr = li & 15, q = li >> 4;
  const short* Ag = P2T + ((size_t)b * Ll + m0) * Ll;
  const short* Bg = cT + ((size_t)b * Hh + h0) * Ll;
  float4v acc[4][4];
#pragma unroll
  for (int i = 0; i < 4; ++i)
#pragma unroll
    for (int j = 0; j < 4; ++j) acc[i][j] = (float4v){0.f, 0.f, 0.f, 0.f};
  stage<128>(As[0], Ag, Ll, t);
  stage<128>(Bs[0], Bg, Ll, t);
  __syncthreads();
  for (int it = 0; it < Ll / 64; ++it) {
    if (it + 1 < Ll / 64) {
      stage<128>(As[(it + 1) & 1], Ag + (it + 1) * 64, Ll, t);
      stage<128>(Bs[(it + 1) & 1], Bg + (it + 1) * 64, Ll, t);
    }
    const short* Ab = As[it & 1];
    const short* Bbuf = Bs[it & 1];
#pragma unroll
    for (int ks = 0; ks < 2; ++ks) {
      int kb = ks * 4 + q;
      short8 af[4], bf4[4];
#pragma unroll
      for (int mt = 0; mt < 4; ++mt) af[mt] = fld(Ab, wy * 64 + mt * 16 + rr, kb);
#pragma unroll
      for (int nt = 0; nt < 4; ++nt) bf4[nt] = fld(Bbuf, wx * 64 + nt * 16 + rr, kb);
#pragma unroll
      for (int mt = 0; mt < 4; ++mt)
#pragma unroll
        for (int nt = 0; nt < 4; ++nt)
          acc[mt][nt] = MFMA(af[mt], bf4[nt], acc[mt][nt]);
    }
    __syncthreads();
  }
#pragma unroll
  for (int nt = 0; nt < 4; ++nt) {
    int h = h0 + wx * 64 + nt * 16 + rr;
#pragma unroll
    for (int mt = 0; mt < 4; ++mt) {
      int mb = m0 + wy * 64 + mt * 16 + q * 4;
      short4v o;
#pragma unroll
      for (int i = 0; i < 4; ++i) o[i] = f2bf(acc[mt][nt][i]);
      *(short4v*)&uT[((size_t)b * Hh + h) * Ll + mb] = o;
    }
  }
}

// ---------------------------------------------------------------------------
// a = P1@c, bvec = P1@u; out = [c | a | c*a | c*bvec]  (2-phase dbuf)
__global__ __launch_bounds__(256) void k_abgemm(
    const short* __restrict__ P1, const short* __restrict__ cT,
    const short* __restrict__ uT, const float* __restrict__ c,
    float* __restrict__ out) {
  // XCD-chunked swizzle (nwg=2048, 256 consecutive units per XCD)
  int flat = blockIdx.x + ((blockIdx.y + (blockIdx.z << 3)) << 3);
  flat = ((flat & 7) << 8) | (flat >> 3);
  const int b = flat >> 6, l0 = ((flat >> 3) & 7) << 7, h0 = (flat & 7) << 6;
  __shared__ __align__(16) short As[2][128 * 64];
  __shared__ __align__(16) short B1s[2][64 * 64];
  __shared__ __align__(16) short B2s[2][64 * 64];
  const int t = threadIdx.x, li = t & 63, w = t >> 6;
  const int wy = w >> 1, wx = w & 1, rr = li & 15, q = li >> 4;
  const short* Ag = P1 + ((size_t)b * Ll + l0) * Ll;
  const short* B1g = cT + ((size_t)b * Hh + h0) * Ll;
  const short* B2g = uT + ((size_t)b * Hh + h0) * Ll;
  float4v aa[4][2], ab[4][2];
#pragma unroll
  for (int i = 0; i < 4; ++i)
#pragma unroll
    for (int j = 0; j < 2; ++j) {
      aa[i][j] = (float4v){0.f, 0.f, 0.f, 0.f};
      ab[i][j] = (float4v){0.f, 0.f, 0.f, 0.f};
    }
  stage<128>(As[0], Ag, Ll, t);
  stage<64>(B1s[0], B1g, Ll, t);
  stage<64>(B2s[0], B2g, Ll, t);
  __syncthreads();
  for (int it = 0; it < Ll / 64; ++it) {
    if (it + 1 < Ll / 64) {
      stage<128>(As[(it + 1) & 1], Ag + (it + 1) * 64, Ll, t);
      stage<64>(B1s[(it + 1) & 1], B1g + (it + 1) * 64, Ll, t);
      stage<64>(B2s[(it + 1) & 1], B2g + (it + 1) * 64, Ll, t);
    }
    const short* Ab = As[it & 1];
    const short* B1b = B1s[it & 1];
    const short* B2b = B2s[it & 1];
#pragma unroll
    for (int ks = 0; ks < 2; ++ks) {
      int kb = ks * 4 + q;
      short8 af[4], b1[2], b2[2];
#pragma unroll
      for (int mt = 0; mt < 4; ++mt) af[mt] = fld(Ab, wy * 64 + mt * 16 + rr, kb);
#pragma unroll
      for (int nt = 0; nt < 2; ++nt) {
        b1[nt] = fld(B1b, wx * 32 + nt * 16 + rr, kb);
        b2[nt] = fld(B2b, wx * 32 + nt * 16 + rr, kb);
      }
#pragma unroll
      for (int mt = 0; mt < 4; ++mt)
#pragma unroll
        for (int nt = 0; nt < 2; ++nt) {
          aa[mt][nt] = MFMA(af[mt], b1[nt], aa[mt][nt]);
          ab[mt][nt] = MFMA(af[mt], b2[nt], ab[mt][nt]);
        }
    }
    __syncthreads();
  }
#pragma unroll
  for (int nt = 0; nt < 2; ++nt) {
    int h = h0 + wx * 32 + nt * 16 + rr;
#pragma unroll
    for (int mt = 0; mt < 4; ++mt) {
#pragma unroll
      for (int i = 0; i < 4; ++i) {
        int l = l0 + wy * 64 + mt * 16 + q * 4 + i;
        float cv = c[((size_t)b * Ll + l) * Hh + h];
        size_t ob = ((size_t)b * Ll + l) * (size_t)(4 * Hh);
        float av = aa[mt][nt][i], bv = ab[mt][nt][i];
        out[ob + h] = cv;
        out[ob + Hh + h] = av;
        out[ob + 2 * Hh + h] = cv * av;
        out[ob + 3 * Hh + h] = cv * bv;
      }
    }
  }
}

// ---------------------------------------------------------------------------
extern "C" void kernel_launch(void* const* d_in, const int* in_sizes, int n_in,
                              void* d_out, int out_size, void* d_ws, size_t ws_size,
                              hipStream_t stream) {
  const float* c = (const float*)d_in[0];
  const int* c_mask = (const int*)d_in[1];
  const float* c_weight = (const float*)d_in[2];
  const float* q_weight = (const float*)d_in[3];
  const float* cq = (const float*)d_in[4];
  const float* bias = (const float*)d_in[5];
  float* out = (float*)d_out;

  // workspace layout with lifetime reuse (~303 MB peak):
  //  [0,134.2M)    S fp32            -> reused by uT (bf16) after p12
  //  [134.2,167.8) cT16
  //  [167.8,201.4) c16               -> P1 low half after sgemm
  //  [201.4,234.9) cbq16             -> P1 high half after sgemm
  //  [234.9,302.0) P2T               -> first 4MB = softmax partials before p12
  //  [302.0,...)   small stats
  char* ws = (char*)d_ws;
  float* S = (float*)ws;
  short* uT = (short*)ws;
  short* cT16 = (short*)(ws + 134217728ull);
  short* c16 = (short*)(ws + 167772160ull);
  short* P1 = (short*)(ws + 167772160ull);
  short* cbq16 = (short*)(ws + 201326592ull);
  short* P2T = (short*)(ws + 234881024ull);
  // partial-stat arrays live in the (not-yet-written) P2T region:
  // consumed by k_comb2 before k_p12 overwrites the region.
  float* rowpmax = (float*)(ws + 234881024ull);
  float* rowpsum = (float*)(ws + 234881024ull + 1048576ull);
  float* colpmax = (float*)(ws + 234881024ull + 2097152ull);
  float* colpsum = (float*)(ws + 234881024ull + 3145728ull);
  float* st = (float*)(ws + 301989888ull);
  float* s0 = st;
  float* s1 = st + 32768;
  float* rowmax = st + 65536;
  float* rowrcp = st + 98304;
  float* colmax = st + 131072;
  float* colrcp = st + 163840;

  k_rowdots<<<dim3(Bb * Ll / 4), dim3(256), 0, stream>>>(c, c_weight, q_weight, s0, s1);
  k_ct<<<dim3(Hh / 64, Ll / 64, Bb), dim3(256), 0, stream>>>(c, cq, cT16, c16, cbq16);
  k_sgemm<<<dim3(Ll / 128, Ll / 128, Bb), dim3(256), 0, stream>>>(
      cbq16, c16, s0, s1, bias, c_mask, S, rowpmax, rowpsum, colpmax, colpsum);
  k_comb2<<<dim3(Bb * Ll / 256, 2), dim3(256), 0, stream>>>(
      rowpmax, rowpsum, colpmax, colpsum, rowmax, rowrcp, colmax, colrcp);
  k_p12<<<dim3(Ll / 64, Ll / 64, Bb), dim3(256), 0, stream>>>(
      S, c_mask, rowmax, rowrcp, colmax, colrcp, P1, P2T);
  k_ugemm<<<dim3(Hh / 128, Ll / 128, Bb), dim3(256), 0, stream>>>(P2T, cT16, uT);
  k_abgemm<<<dim3(Hh / 64, Ll / 128, Bb), dim3(256), 0, stream>>>(P1, cT16, uT, c, out);
}

// Round 3
// 687.803 us; speedup vs baseline: 1.0460x; 1.0460x over previous
//
#include <hip/hip_runtime.h>
#include <hip/hip_bf16.h>
#include <stdint.h>

constexpr int Bb = 32;
constexpr int Ll = 1024;
constexpr int Hh = 512;

typedef __attribute__((ext_vector_type(8))) short short8;
typedef __attribute__((ext_vector_type(4))) short short4v;
typedef __attribute__((ext_vector_type(4))) float float4v;
typedef __attribute__((ext_vector_type(4))) int int4v;

__device__ inline short f2bf(float f) {
  union { float f; uint32_t u; } v; v.f = f;
  uint32_t r = (v.u + 0x7FFF + ((v.u >> 16) & 1)) >> 16;
  return (short)r;
}

#define MFMA(a, b, c) __builtin_amdgcn_mfma_f32_16x16x32_bf16(a, b, c, 0, 0, 0)

// raw barrier fenced against compiler reordering on both sides
#define BAR()                                   \
  do {                                          \
    __builtin_amdgcn_sched_barrier(0);          \
    __builtin_amdgcn_s_barrier();               \
    __builtin_amdgcn_sched_barrier(0);          \
  } while (0)
// counted waits (keep prefetch loads in flight across barriers)
#define WAIT_VM8() asm volatile("s_waitcnt vmcnt(8)" ::: "memory")
#define WAIT_VM0() asm volatile("s_waitcnt vmcnt(0)" ::: "memory")
#define WAIT_LGKM0() asm volatile("s_waitcnt lgkmcnt(0)" ::: "memory")

// async 16B global->LDS (dest = wave-uniform base + lane*16)
__device__ inline void gl_lds(const short* g, short* l) {
  __builtin_amdgcn_global_load_lds(
      (const __attribute__((address_space(1))) unsigned int*)g,
      (__attribute__((address_space(3))) unsigned int*)l, 16, 0, 0);
}

// Stage ROWS x 64 bf16 tile from row-major global (stride sk) into LDS.
// LDS layout: lds[row*64 + (kb ^ (row&7))*8 .. +8] = g[row*sk + kb*8 .. +8]
// Per-thread vmem instruction count: ROWS/32  (128 -> 4, 64 -> 2).
template <int ROWS>
__device__ inline void stage(short* lds, const short* g, int sk, int t) {
  const int w = t >> 6;
  const int kbg = (t & 7) ^ ((t >> 3) & 7);
#pragma unroll
  for (int r = 0; r < ROWS / 32; ++r) {
    int row = r * 32 + (t >> 3);
    gl_lds(g + (size_t)row * sk + kbg * 8, lds + (r * 32 + w * 8) * 64);
  }
}

// fragment load: 8 contiguous bf16 (k) for row, k-block kb (global k index kb*8)
__device__ inline short8 fld(const short* lds, int row, int kb) {
  return *(const short8*)(lds + row * 64 + ((kb ^ (row & 7)) << 3));
}

// ---------------------------------------------------------------------------
// per-row dots  s0[b,l] = c.cw,  s1[b,l] = c.qw
__global__ __launch_bounds__(256) void k_rowdots(
    const float* __restrict__ c, const float* __restrict__ cw,
    const float* __restrict__ qw, float* __restrict__ s0, float* __restrict__ s1) {
  int row = blockIdx.x * 4 + (threadIdx.x >> 6);
  int lane = threadIdx.x & 63;
  const float* cr = c + (size_t)row * Hh;
  float d0 = 0.f, d1 = 0.f;
#pragma unroll
  for (int i = 0; i < Hh / 64; ++i) {
    int h = lane + i * 64;
    float v = cr[h];
    d0 = fmaf(v, cw[h], d0);
    d1 = fmaf(v, qw[h], d1);
  }
#pragma unroll
  for (int off = 32; off > 0; off >>= 1) {
    d0 += __shfl_down(d0, off);
    d1 += __shfl_down(d1, off);
  }
  if (lane == 0) { s0[row] = d0; s1[row] = d1; }
}

// ---------------------------------------------------------------------------
// FUSED prep: one read of c ->
//   cT16[b][h][l] (bf16 transpose), c16 = bf16(c), cbq16 = bf16(c*cq)
__global__ __launch_bounds__(256) void k_ct(
    const float* __restrict__ c, const float* __restrict__ cq,
    short* __restrict__ cT, short* __restrict__ c16, short* __restrict__ cbq16) {
  const int b = blockIdx.z, h0 = blockIdx.x * 64, l0 = blockIdx.y * 64;
  __shared__ short T[64 * 65];
  const int t = threadIdx.x, rl = t >> 4, c4 = (t & 15) * 4;
  float4v qv = *(const float4v*)&cq[h0 + c4];
#pragma unroll
  for (int p = 0; p < 4; ++p) {
    int ll = rl + p * 16;
    size_t gi = ((size_t)(b * Ll + l0 + ll)) * Hh + h0 + c4;
    float4v v = *(const float4v*)&c[gi];
    short4v o, oq;
#pragma unroll
    for (int j = 0; j < 4; ++j) {
      short bv = f2bf(v[j]);
      T[ll * 65 + c4 + j] = bv;
      o[j] = bv;
      oq[j] = f2bf(v[j] * qv[j]);
    }
    *(short4v*)&c16[gi] = o;
    *(short4v*)&cbq16[gi] = oq;
  }
  __syncthreads();
#pragma unroll
  for (int p = 0; p < 4; ++p) {
    int hh = rl + p * 16;
    short4v o;
#pragma unroll
    for (int j = 0; j < 4; ++j) o[j] = T[(c4 + j) * 65 + hh];
    *(short4v*)&cT[((size_t)(b * Hh + h0 + hh)) * Ll + l0 + c4] = o;
  }
}

// ---------------------------------------------------------------------------
// S = cbq16 @ c16^T + s0 + s1 + bias   (fp32 out)
// dbuf + counted-vmcnt pipeline; fused row/col softmax partial stats.
__global__ __launch_bounds__(256) void k_sgemm(
    const short* __restrict__ Aq, const short* __restrict__ Bc,
    const float* __restrict__ s0, const float* __restrict__ s1,
    const float* __restrict__ bias, const int* __restrict__ c_mask,
    float* __restrict__ S,
    float* __restrict__ rowpmax, float* __restrict__ rowpsum,
    float* __restrict__ colpmax, float* __restrict__ colpsum) {
  // XCD-chunked swizzle (nwg=2048, 256 consecutive units per XCD)
  int flat = blockIdx.x + ((blockIdx.y + (blockIdx.z << 3)) << 3);
  flat = ((flat & 7) << 8) | (flat >> 3);
  const int b = flat >> 6, l0 = ((flat >> 3) & 7) << 7, m0 = (flat & 7) << 7;
  __shared__ __align__(16) short As[2][128 * 64];
  __shared__ __align__(16) short Bs[2][128 * 64];
  const int t = threadIdx.x, li = t & 63, w = t >> 6;
  const int wy = w >> 1, wx = w & 1, rr = li & 15, q = li >> 4;
  const short* Ag = Aq + ((size_t)b * Ll + l0) * Hh;
  const short* Bg = Bc + ((size_t)b * Ll + m0) * Hh;
  float4v acc[4][4];
#pragma unroll
  for (int i = 0; i < 4; ++i)
#pragma unroll
    for (int j = 0; j < 4; ++j) acc[i][j] = (float4v){0.f, 0.f, 0.f, 0.f};
  auto compute = [&](const short* Ab, const short* Bbuf) {
#pragma unroll
    for (int ks = 0; ks < 2; ++ks) {
      int kb = ks * 4 + q;
      short8 af[4], bf4[4];
#pragma unroll
      for (int mt = 0; mt < 4; ++mt) af[mt] = fld(Ab, wy * 64 + mt * 16 + rr, kb);
#pragma unroll
      for (int nt = 0; nt < 4; ++nt) bf4[nt] = fld(Bbuf, wx * 64 + nt * 16 + rr, kb);
#pragma unroll
      for (int mt = 0; mt < 4; ++mt)
#pragma unroll
        for (int nt = 0; nt < 4; ++nt)
          acc[mt][nt] = MFMA(af[mt], bf4[nt], acc[mt][nt]);
    }
  };
  stage<128>(As[0], Ag, Hh, t);
  stage<128>(Bs[0], Bg, Hh, t);
  for (int it = 0; it < Hh / 64 - 1; ++it) {
    stage<128>(As[(it + 1) & 1], Ag + (it + 1) * 64, Hh, t);
    stage<128>(Bs[(it + 1) & 1], Bg + (it + 1) * 64, Hh, t);
    WAIT_VM8();   // current tile's 8 loads done; 8 prefetch stay in flight
    BAR();
    compute(As[it & 1], Bs[it & 1]);
    WAIT_LGKM0(); // my reads of this buffer complete before it is re-staged
    BAR();
  }
  WAIT_VM0();
  BAR();
  compute(As[(Hh / 64 - 1) & 1], Bs[(Hh / 64 - 1) & 1]);
  WAIT_LGKM0();
  BAR();
  // ---- epilogue: finalize S in registers ----
  const float bsc = bias[0];
  float s1v[4]; int mkm[4];
#pragma unroll
  for (int nt = 0; nt < 4; ++nt) {
    int m = m0 + wx * 64 + nt * 16 + rr;
    s1v[nt] = s1[b * Ll + m] + bsc;
    mkm[nt] = c_mask[b * Ll + m];
  }
  int mkl[4][4];
#pragma unroll
  for (int mt = 0; mt < 4; ++mt)
#pragma unroll
    for (int i = 0; i < 4; ++i) {
      int l = l0 + wy * 64 + mt * 16 + q * 4 + i;
      float s0v = s0[b * Ll + l];
      mkl[mt][i] = c_mask[b * Ll + l];
#pragma unroll
      for (int nt = 0; nt < 4; ++nt) acc[mt][nt][i] += s0v + s1v[nt];
    }
  // store S
  float* Sb = S + (size_t)b * Ll * Ll;
#pragma unroll
  for (int nt = 0; nt < 4; ++nt) {
    int m = m0 + wx * 64 + nt * 16 + rr;
#pragma unroll
    for (int mt = 0; mt < 4; ++mt)
#pragma unroll
      for (int i = 0; i < 4; ++i) {
        int l = l0 + wy * 64 + mt * 16 + q * 4 + i;
        Sb[(size_t)l * Ll + m] = acc[mt][nt][i];
      }
  }
  // ---- fused softmax partial stats (tile live in acc) ----
  float* red = (float*)As;  // 256-float scratch; k-loop LDS use is done
  const size_t rbase = (size_t)(m0 >> 7) * (Bb * Ll) + (size_t)b * Ll + l0;
  const size_t cbase = (size_t)(l0 >> 7) * (Bb * Ll) + (size_t)b * Ll + m0;
  // row max over the tile's 128 columns (mask on m)
  float rv[16];
#pragma unroll
  for (int mt = 0; mt < 4; ++mt)
#pragma unroll
    for (int i = 0; i < 4; ++i) {
      float v = -INFINITY;
#pragma unroll
      for (int nt = 0; nt < 4; ++nt) v = mkm[nt] ? fmaxf(v, acc[mt][nt][i]) : v;
      rv[mt * 4 + i] = v;
    }
#pragma unroll
  for (int off = 1; off < 16; off <<= 1)
#pragma unroll
    for (int j = 0; j < 16; ++j) rv[j] = fmaxf(rv[j], __shfl_xor(rv[j], off));
  if (rr == 0)
#pragma unroll
    for (int j = 0; j < 16; ++j)
      red[wx * 128 + wy * 64 + (j >> 2) * 16 + q * 4 + (j & 3)] = rv[j];
  __syncthreads();
  if (t < 128) {
    float M = fmaxf(red[t], red[128 + t]);
    red[t] = M;
    rowpmax[rbase + t] = M;
  }
  __syncthreads();
  // row sumexp vs tile max
#pragma unroll
  for (int mt = 0; mt < 4; ++mt)
#pragma unroll
    for (int i = 0; i < 4; ++i) {
      float M = red[wy * 64 + mt * 16 + q * 4 + i];
      float sacc = 0.f;
      if (M > -INFINITY) {
#pragma unroll
        for (int nt = 0; nt < 4; ++nt)
          sacc += mkm[nt] ? __expf(acc[mt][nt][i] - M) : 0.f;
      }
      rv[mt * 4 + i] = sacc;
    }
#pragma unroll
  for (int off = 1; off < 16; off <<= 1)
#pragma unroll
    for (int j = 0; j < 16; ++j) rv[j] += __shfl_xor(rv[j], off);
  __syncthreads();
  if (rr == 0)
#pragma unroll
    for (int j = 0; j < 16; ++j)
      red[wx * 128 + wy * 64 + (j >> 2) * 16 + q * 4 + (j & 3)] = rv[j];
  __syncthreads();
  if (t < 128) rowpsum[rbase + t] = red[t] + red[128 + t];
  // col max over the tile's 128 rows (mask on l)
  float cv[4];
#pragma unroll
  for (int nt = 0; nt < 4; ++nt) {
    float v = -INFINITY;
#pragma unroll
    for (int mt = 0; mt < 4; ++mt)
#pragma unroll
      for (int i = 0; i < 4; ++i) v = mkl[mt][i] ? fmaxf(v, acc[mt][nt][i]) : v;
    cv[nt] = v;
  }
#pragma unroll
  for (int nt = 0; nt < 4; ++nt) {
    cv[nt] = fmaxf(cv[nt], __shfl_xor(cv[nt], 16));
    cv[nt] = fmaxf(cv[nt], __shfl_xor(cv[nt], 32));
  }
  __syncthreads();
  if (q == 0)
#pragma unroll
    for (int nt = 0; nt < 4; ++nt) red[wy * 128 + wx * 64 + nt * 16 + rr] = cv[nt];
  __syncthreads();
  if (t < 128) {
    float M = fmaxf(red[t], red[128 + t]);
    red[t] = M;
    colpmax[cbase + t] = M;
  }
  __syncthreads();
  // col sumexp vs tile max
#pragma unroll
  for (int nt = 0; nt < 4; ++nt) {
    float M = red[wx * 64 + nt * 16 + rr];
    float sacc = 0.f;
    if (M > -INFINITY) {
#pragma unroll
      for (int mt = 0; mt < 4; ++mt)
#pragma unroll
        for (int i = 0; i < 4; ++i)
          sacc += mkl[mt][i] ? __expf(acc[mt][nt][i] - M) : 0.f;
    }
    cv[nt] = sacc;
  }
#pragma unroll
  for (int nt = 0; nt < 4; ++nt) {
    cv[nt] += __shfl_xor(cv[nt], 16);
    cv[nt] += __shfl_xor(cv[nt], 32);
  }
  __syncthreads();
  if (q == 0)
#pragma unroll
    for (int nt = 0; nt < 4; ++nt) red[wy * 128 + wx * 64 + nt * 16 + rr] = cv[nt];
  __syncthreads();
  if (t < 128) colpsum[cbase + t] = red[t] + red[128 + t];
}

// ---------------------------------------------------------------------------
// combine 8 chunked partials -> max + 1/sum; blockIdx.y: 0=row stats, 1=col
__global__ __launch_bounds__(256) void k_comb2(
    const float* __restrict__ rpm, const float* __restrict__ rps,
    const float* __restrict__ cpm, const float* __restrict__ cps,
    float* __restrict__ rmax, float* __restrict__ rrcp,
    float* __restrict__ cmax, float* __restrict__ crcp) {
  int i = blockIdx.x * 256 + threadIdx.x;
  const float* pmax = blockIdx.y ? cpm : rpm;
  const float* psum = blockIdx.y ? cps : rps;
  float* omax = blockIdx.y ? cmax : rmax;
  float* orcp = blockIdx.y ? crcp : rrcp;
  float M = -INFINITY;
#pragma unroll
  for (int k = 0; k < 8; ++k) M = fmaxf(M, pmax[k * (Bb * Ll) + i]);
  float s = 0.f;
#pragma unroll
  for (int k = 0; k < 8; ++k) {
    float pm = pmax[k * (Bb * Ll) + i];
    if (pm > -INFINITY) s += psum[k * (Bb * Ll) + i] * __expf(pm - M);
  }
  omax[i] = M;
  orcp[i] = 1.f / s;
}

// ---------------------------------------------------------------------------
// FUSED softmax emit: one S read ->
//   P1[b][l][m]  = mask[m]*exp(S-rowmax[l])*rowrcp[l]   (bf16, direct)
//   P2T[b][m][l] = mask[l]*exp(S-colmax[m])*colrcp[m]   (bf16, transposed)
__global__ __launch_bounds__(256) void k_p12(
    const float* __restrict__ S, const int* __restrict__ c_mask,
    const float* __restrict__ rowmax, const float* __restrict__ rowrcp,
    const float* __restrict__ colmax, const float* __restrict__ colrcp,
    short* __restrict__ P1, short* __restrict__ P2T) {
  const int b = blockIdx.z, m0 = blockIdx.x * 64, l0 = blockIdx.y * 64;
  __shared__ short T[64 * 65];
  const int t = threadIdx.x, rl = t >> 4, c4 = (t & 15) * 4;
  const float* Sb = S + (size_t)b * Ll * Ll;
  float4v cm = *(const float4v*)&colmax[b * Ll + m0 + c4];
  float4v cr = *(const float4v*)&colrcp[b * Ll + m0 + c4];
  int4v mkm = *(const int4v*)&c_mask[b * Ll + m0 + c4];
#pragma unroll
  for (int p = 0; p < 4; ++p) {
    int ll = rl + p * 16;
    int gl = b * Ll + l0 + ll;
    int mkl = c_mask[gl];
    float rm = rowmax[gl], rrc = rowrcp[gl];
    float4v v = *(const float4v*)&Sb[(size_t)(l0 + ll) * Ll + m0 + c4];
    short4v o1;
#pragma unroll
    for (int j = 0; j < 4; ++j) {
      o1[j] = mkm[j] ? f2bf(__expf(v[j] - rm) * rrc) : (short)0;
      T[ll * 65 + c4 + j] = mkl ? f2bf(__expf(v[j] - cm[j]) * cr[j]) : (short)0;
    }
    *(short4v*)&P1[(size_t)gl * Ll + m0 + c4] = o1;
  }
  __syncthreads();
#pragma unroll
  for (int p = 0; p < 4; ++p) {
    int mm = rl + p * 16;
    short4v o;
#pragma unroll
    for (int j = 0; j < 4; ++j) o[j] = T[(c4 + j) * 65 + mm];
    *(short4v*)&P2T[((size_t)(b * Ll + m0 + mm)) * Ll + l0 + c4] = o;
  }
}

// ---------------------------------------------------------------------------
// uT[b][h][m] = (P2T @ cT^T)^T  bf16   (dbuf + counted vmcnt)
__global__ __launch_bounds__(256) void k_ugemm(
    const short* __restrict__ P2T, const short* __restrict__ cT,
    short* __restrict__ uT) {
  // XCD-chunked swizzle (nwg=1024, 128 consecutive units per XCD)
  int flat = blockIdx.x + ((blockIdx.y + (blockIdx.z << 3)) << 2);
  flat = ((flat & 7) << 7) | (flat >> 3);
  const int b = flat >> 5, m0 = ((flat >> 2) & 7) << 7, h0 = (flat & 3) << 7;
  __shared__ __align__(16) short As[2][128 * 64];
  __shared__ __align__(16) short Bs[2][128 * 64];
  const int t = threadIdx.x, li = t & 63, w = t >> 6;
  const int wy = w >> 1, wx = w & 1, rr = li & 15, q = li >> 4;
  const short* Ag = P2T + ((size_t)b * Ll + m0) * Ll;
  const short* Bg = cT + ((size_t)b * Hh + h0) * Ll;
  float4v acc[4][4];
#pragma unroll
  for (int i = 0; i < 4; ++i)
#pragma unroll
    for (int j = 0; j < 4; ++j) acc[i][j] = (float4v){0.f, 0.f, 0.f, 0.f};
  auto compute = [&](const short* Ab, const short* Bbuf) {
#pragma unroll
    for (int ks = 0; ks < 2; ++ks) {
      int kb = ks * 4 + q;
      short8 af[4], bf4[4];
#pragma unroll
      for (int mt = 0; mt < 4; ++mt) af[mt] = fld(Ab, wy * 64 + mt * 16 + rr, kb);
#pragma unroll
      for (int nt = 0; nt < 4; ++nt) bf4[nt] = fld(Bbuf, wx * 64 + nt * 16 + rr, kb);
#pragma unroll
      for (int mt = 0; mt < 4; ++mt)
#pragma unroll
        for (int nt = 0; nt < 4; ++nt)
          acc[mt][nt] = MFMA(af[mt], bf4[nt], acc[mt][nt]);
    }
  };
  stage<128>(As[0], Ag, Ll, t);
  stage<128>(Bs[0], Bg, Ll, t);
  for (int it = 0; it < Ll / 64 - 1; ++it) {
    stage<128>(As[(it + 1) & 1], Ag + (it + 1) * 64, Ll, t);
    stage<128>(Bs[(it + 1) & 1], Bg + (it + 1) * 64, Ll, t);
    WAIT_VM8();
    BAR();
    compute(As[it & 1], Bs[it & 1]);
    WAIT_LGKM0();
    BAR();
  }
  WAIT_VM0();
  BAR();
  compute(As[(Ll / 64 - 1) & 1], Bs[(Ll / 64 - 1) & 1]);
#pragma unroll
  for (int nt = 0; nt < 4; ++nt) {
    int h = h0 + wx * 64 + nt * 16 + rr;
#pragma unroll
    for (int mt = 0; mt < 4; ++mt) {
      int mb = m0 + wy * 64 + mt * 16 + q * 4;
      short4v o;
#pragma unroll
      for (int i = 0; i < 4; ++i) o[i] = f2bf(acc[mt][nt][i]);
      *(short4v*)&uT[((size_t)b * Hh + h) * Ll + mb] = o;
    }
  }
}

// ---------------------------------------------------------------------------
// a = P1@c, bvec = P1@u; out = [c | a | c*a | c*bvec]  (dbuf + counted vmcnt)
__global__ __launch_bounds__(256) void k_abgemm(
    const short* __restrict__ P1, const short* __restrict__ cT,
    const short* __restrict__ uT, const float* __restrict__ c,
    float* __restrict__ out) {
  // XCD-chunked swizzle (nwg=2048, 256 consecutive units per XCD)
  int flat = blockIdx.x + ((blockIdx.y + (blockIdx.z << 3)) << 3);
  flat = ((flat & 7) << 8) | (flat >> 3);
  const int b = flat >> 6, l0 = ((flat >> 3) & 7) << 7, h0 = (flat & 7) << 6;
  __shared__ __align__(16) short As[2][128 * 64];
  __shared__ __align__(16) short B1s[2][64 * 64];
  __shared__ __align__(16) short B2s[2][64 * 64];
  const int t = threadIdx.x, li = t & 63, w = t >> 6;
  const int wy = w >> 1, wx = w & 1, rr = li & 15, q = li >> 4;
  const short* Ag = P1 + ((size_t)b * Ll + l0) * Ll;
  const short* B1g = cT + ((size_t)b * Hh + h0) * Ll;
  const short* B2g = uT + ((size_t)b * Hh + h0) * Ll;
  float4v aa[4][2], ab[4][2];
#pragma unroll
  for (int i = 0; i < 4; ++i)
#pragma unroll
    for (int j = 0; j < 2; ++j) {
      aa[i][j] = (float4v){0.f, 0.f, 0.f, 0.f};
      ab[i][j] = (float4v){0.f, 0.f, 0.f, 0.f};
    }
  auto compute = [&](const short* Ab, const short* B1b, const short* B2b) {
#pragma unroll
    for (int ks = 0; ks < 2; ++ks) {
      int kb = ks * 4 + q;
      short8 af[4], b1[2], b2[2];
#pragma unroll
      for (int mt = 0; mt < 4; ++mt) af[mt] = fld(Ab, wy * 64 + mt * 16 + rr, kb);
#pragma unroll
      for (int nt = 0; nt < 2; ++nt) {
        b1[nt] = fld(B1b, wx * 32 + nt * 16 + rr, kb);
        b2[nt] = fld(B2b, wx * 32 + nt * 16 + rr, kb);
      }
#pragma unroll
      for (int mt = 0; mt < 4; ++mt)
#pragma unroll
        for (int nt = 0; nt < 2; ++nt) {
          aa[mt][nt] = MFMA(af[mt], b1[nt], aa[mt][nt]);
          ab[mt][nt] = MFMA(af[mt], b2[nt], ab[mt][nt]);
        }
    }
  };
  stage<128>(As[0], Ag, Ll, t);
  stage<64>(B1s[0], B1g, Ll, t);
  stage<64>(B2s[0], B2g, Ll, t);
  for (int it = 0; it < Ll / 64 - 1; ++it) {
    stage<128>(As[(it + 1) & 1], Ag + (it + 1) * 64, Ll, t);
    stage<64>(B1s[(it + 1) & 1], B1g + (it + 1) * 64, Ll, t);
    stage<64>(B2s[(it + 1) & 1], B2g + (it + 1) * 64, Ll, t);
    WAIT_VM8();
    BAR();
    compute(As[it & 1], B1s[it & 1], B2s[it & 1]);
    WAIT_LGKM0();
    BAR();
  }
  WAIT_VM0();
  BAR();
  compute(As[(Ll / 64 - 1) & 1], B1s[(Ll / 64 - 1) & 1], B2s[(Ll / 64 - 1) & 1]);
#pragma unroll
  for (int nt = 0; nt < 2; ++nt) {
    int h = h0 + wx * 32 + nt * 16 + rr;
#pragma unroll
    for (int mt = 0; mt < 4; ++mt) {
#pragma unroll
      for (int i = 0; i < 4; ++i) {
        int l = l0 + wy * 64 + mt * 16 + q * 4 + i;
        float cv = c[((size_t)b * Ll + l) * Hh + h];
        size_t ob = ((size_t)b * Ll + l) * (size_t)(4 * Hh);
        float av = aa[mt][nt][i], bv = ab[mt][nt][i];
        out[ob + h] = cv;
        out[ob + Hh + h] = av;
        out[ob + 2 * Hh + h] = cv * av;
        out[ob + 3 * Hh + h] = cv * bv;
      }
    }
  }
}

// ---------------------------------------------------------------------------
extern "C" void kernel_launch(void* const* d_in, const int* in_sizes, int n_in,
                              void* d_out, int out_size, void* d_ws, size_t ws_size,
                              hipStream_t stream) {
  const float* c = (const float*)d_in[0];
  const int* c_mask = (const int*)d_in[1];
  const float* c_weight = (const float*)d_in[2];
  const float* q_weight = (const float*)d_in[3];
  const float* cq = (const float*)d_in[4];
  const float* bias = (const float*)d_in[5];
  float* out = (float*)d_out;

  // workspace layout with lifetime reuse (~303 MB peak):
  //  [0,134.2M)    S fp32            -> reused by uT (bf16) after p12
  //  [134.2,167.8) cT16
  //  [167.8,201.4) c16               -> P1 low half after sgemm
  //  [201.4,234.9) cbq16             -> P1 high half after sgemm
  //  [234.9,302.0) P2T               -> first 4MB = softmax partials before p12
  //  [302.0,...)   small stats
  char* ws = (char*)d_ws;
  float* S = (float*)ws;
  short* uT = (short*)ws;
  short* cT16 = (short*)(ws + 134217728ull);
  short* c16 = (short*)(ws + 167772160ull);
  short* P1 = (short*)(ws + 167772160ull);
  short* cbq16 = (short*)(ws + 201326592ull);
  short* P2T = (short*)(ws + 234881024ull);
  // partial-stat arrays live in the (not-yet-written) P2T region:
  // consumed by k_comb2 before k_p12 overwrites the region.
  float* rowpmax = (float*)(ws + 234881024ull);
  float* rowpsum = (float*)(ws + 234881024ull + 1048576ull);
  float* colpmax = (float*)(ws + 234881024ull + 2097152ull);
  float* colpsum = (float*)(ws + 234881024ull + 3145728ull);
  float* st = (float*)(ws + 301989888ull);
  float* s0 = st;
  float* s1 = st + 32768;
  float* rowmax = st + 65536;
  float* rowrcp = st + 98304;
  float* colmax = st + 131072;
  float* colrcp = st + 163840;

  k_rowdots<<<dim3(Bb * Ll / 4), dim3(256), 0, stream>>>(c, c_weight, q_weight, s0, s1);
  k_ct<<<dim3(Hh / 64, Ll / 64, Bb), dim3(256), 0, stream>>>(c, cq, cT16, c16, cbq16);
  k_sgemm<<<dim3(Ll / 128, Ll / 128, Bb), dim3(256), 0, stream>>>(
      cbq16, c16, s0, s1, bias, c_mask, S, rowpmax, rowpsum, colpmax, colpsum);
  k_comb2<<<dim3(Bb * Ll / 256, 2), dim3(256), 0, stream>>>(
      rowpmax, rowpsum, colpmax, colpsum, rowmax, rowrcp, colmax, colrcp);
  k_p12<<<dim3(Ll / 64, Ll / 64, Bb), dim3(256), 0, stream>>>(
      S, c_mask, rowmax, rowrcp, colmax, colrcp, P1, P2T);
  k_ugemm<<<dim3(Hh / 128, Ll / 128, Bb), dim3(256), 0, stream>>>(P2T, cT16, uT);
  k_abgemm<<<dim3(Hh / 64, Ll / 128, Bb), dim3(256), 0, stream>>>(P1, cT16, uT, c, out);
}